// Round 13
// baseline (298.508 us; speedup 1.0000x reference)
//
#include <hip/hip_runtime.h>
#include <math.h>

#define N_NODES 50000
#define E_RAWN  600000
#define FEAT    64
#define HID     64
#define HEADS   4
#define NSUB    32
#define NGRAPH  128
#define NB_SCAN ((N_NODES + 255) / 256)   // 196
#define G2_NODES 128

__device__ __forceinline__ float leaky02(float v) { return v >= 0.f ? v : 0.2f * v; }
__device__ __forceinline__ float elu1(float v)    { return v > 0.f ? v : expm1f(v); }

// bf16 pack/unpack (RNE), 2 per uint
__device__ __forceinline__ unsigned bf2pack(float a, float b) {
    unsigned ua = __float_as_uint(a), ub = __float_as_uint(b);
    ua = (ua + 0x7FFFu + ((ua >> 16) & 1u)) >> 16;
    ub = (ub + 0x7FFFu + ((ub >> 16) & 1u)) >> 16;
    return ua | (ub << 16);
}
__device__ __forceinline__ float bflo(unsigned p) { return __uint_as_float(p << 16); }
__device__ __forceinline__ float bfhi(unsigned p) { return __uint_as_float(p & 0xFFFF0000u); }
__device__ __forceinline__ float bfs(unsigned short v) { return __uint_as_float((unsigned)v << 16); }

// ---------- Phase A merged: substructure accumulate (blocks 0-255) + edge count (blocks 256-511) ----------
__global__ void k_prep(const float* __restrict__ x,
                       float* __restrict__ ssum, float* __restrict__ scnt,
                       const int* __restrict__ dst, int* __restrict__ cnt) {
    int tid = threadIdx.x;
    if (blockIdx.x < 256) {
        __shared__ float lsum[NSUB * FEAT];
        __shared__ float lcnt[NSUB];
        for (int i = tid; i < NSUB * FEAT; i += 256) lsum[i] = 0.f;
        if (tid < NSUB) lcnt[tid] = 0.f;
        __syncthreads();
        const int total = N_NODES * FEAT;
        for (int idx = blockIdx.x * 256 + tid; idx < total; idx += 256 * 256) {
            int node = idx >> 6, f = idx & 63;
            int sid = (int)x[node * FEAT + 5];
            atomicAdd(&lsum[sid * FEAT + f], x[idx]);
            if (f == 0) atomicAdd(&lcnt[sid], 1.f);
        }
        __syncthreads();
        for (int i = tid; i < NSUB * FEAT; i += 256) atomicAdd(&ssum[i], lsum[i]);
        if (tid < NSUB) atomicAdd(&scnt[tid], lcnt[tid]);
    } else {
        for (int e = (blockIdx.x - 256) * 256 + tid; e < E_RAWN; e += 256 * 256)
            atomicAdd(&cnt[dst[e]], 1);
    }
}

// ---------- Merged: scan1 (blocks 0-195) + substructure MLP/softmax (block 196) ----------
__global__ void k_mlp_scan1(const int* __restrict__ cnt, int* __restrict__ offs, int* __restrict__ bsum,
                            const float* __restrict__ ssum, const float* __restrict__ scnt,
                            const float* __restrict__ w_sa1, const float* __restrict__ b_sa1,
                            const float* __restrict__ w_sa2, const float* __restrict__ b_sa2,
                            float* __restrict__ wsub) {
    int tid = threadIdx.x;
    if (blockIdx.x == NB_SCAN) {
        __shared__ float logits[NSUB];
        int s = tid;
        if (s < NSUB) {
            float c = fmaxf(scnt[s], 1.f);
            float sm[FEAT];
            for (int k = 0; k < FEAT; k++) sm[k] = ssum[s * FEAT + k] / c;
            float logit = b_sa2[0];
            for (int j = 0; j < 32; j++) {
                float hj = b_sa1[j];
                for (int k = 0; k < FEAT; k++) hj += sm[k] * w_sa1[k * 32 + j];
                hj = leaky02(hj);
                logit += hj * w_sa2[j];
            }
            logits[s] = logit;
        }
        __syncthreads();
        if (s < NSUB) {
            float m = -1e30f;
            for (int i = 0; i < NSUB; i++) m = fmaxf(m, logits[i]);
            float dsum = 0.f;
            for (int i = 0; i < NSUB; i++) dsum += expf(logits[i] - m);
            wsub[s] = expf(logits[s] - m) / dsum;
        }
        return;
    }
    __shared__ int sd[256];
    int i = blockIdx.x * 256 + tid;
    int v = (i < N_NODES) ? cnt[i] : 0;
    sd[tid] = v;
    for (int off = 1; off < 256; off <<= 1) {
        __syncthreads();
        int tv = (tid >= off) ? sd[tid - off] : 0;
        __syncthreads();
        sd[tid] += tv;
    }
    __syncthreads();
    if (i < N_NODES) offs[i] = sd[tid] - v;
    if (tid == 255) bsum[blockIdx.x] = sd[255];
}

// ---------- Phase B: h1 = [x, atom_w] @ W1 — 64 nodes/block, W1 chunks in LDS ----------
__global__ __launch_bounds__(256) void k_gemm1(const float* __restrict__ x,
                                               const float* __restrict__ wsub,
                                               const float* __restrict__ W1,
                                               const float* __restrict__ att_s1,
                                               const float* __restrict__ att_d1,
                                               unsigned* __restrict__ h1b,
                                               float* __restrict__ as1, float* __restrict__ ad1) {
    __shared__ float xs[65][68];    // [k][node], 272B rows
    __shared__ float ws[16][260];   // one 16-row W1 chunk, [k][col]
    int t = threadIdx.x;
    int gbase = blockIdx.x * 64;
    for (int idx = t; idx < 64 * 64; idx += 256) {
        int n = idx >> 6, f = idx & 63;
        int g = gbase + n;
        xs[f][n] = (g < N_NODES) ? x[(size_t)g * FEAT + f] : 0.f;
    }
    __syncthreads();
    if (t < 64) {
        int sid = (int)xs[5][t];
        xs[64][t] = wsub[sid & (NSUB - 1)];
    }

    int m = t & 31, q = t >> 5;
    int c0 = m * 8, q8 = q * 8;
    float accs[64];                 // [col c][node j] = accs[c*8+j]
    #pragma unroll
    for (int i = 0; i < 64; ++i) accs[i] = 0.f;

    for (int kc = 0; kc < 4; ++kc) {
        __syncthreads();            // ws reuse guard (covers xs[64] write before kc=0)
        #pragma unroll
        for (int s = 0; s < 16; ++s)
            ws[s][t] = W1[(size_t)(kc * 16 + s) * 256 + t];
        __syncthreads();
        #pragma unroll
        for (int kk = 0; kk < 16; ++kk) {
            float4 wa = *(const float4*)(&ws[kk][c0]);
            float4 wb = *(const float4*)(&ws[kk][c0 + 4]);
            float4 xa = *(const float4*)(&xs[kc * 16 + kk][q8]);
            float4 xb = *(const float4*)(&xs[kc * 16 + kk][q8 + 4]);
            float wv[8] = {wa.x, wa.y, wa.z, wa.w, wb.x, wb.y, wb.z, wb.w};
            float xv[8] = {xa.x, xa.y, xa.z, xa.w, xb.x, xb.y, xb.z, xb.w};
            #pragma unroll
            for (int c = 0; c < 8; ++c)
                #pragma unroll
                for (int j = 0; j < 8; ++j)
                    accs[c * 8 + j] += wv[c] * xv[j];
        }
    }
    {   // k = 64: atom_w row, direct from global (1 KB, L2-hot)
        float4 wa = *(const float4*)(W1 + (size_t)64 * 256 + c0);
        float4 wb = *(const float4*)(W1 + (size_t)64 * 256 + c0 + 4);
        float4 xa = *(const float4*)(&xs[64][q8]);
        float4 xb = *(const float4*)(&xs[64][q8 + 4]);
        float wv[8] = {wa.x, wa.y, wa.z, wa.w, wb.x, wb.y, wb.z, wb.w};
        float xv[8] = {xa.x, xa.y, xa.z, xa.w, xb.x, xb.y, xb.z, xb.w};
        #pragma unroll
        for (int c = 0; c < 8; ++c)
            #pragma unroll
            for (int j = 0; j < 8; ++j)
                accs[c * 8 + j] += wv[c] * xv[j];
    }

    float atts[8], attd[8];
    #pragma unroll
    for (int c = 0; c < 8; ++c) { atts[c] = att_s1[c0 + c]; attd[c] = att_d1[c0 + c]; }
    int h = m >> 3;
    #pragma unroll
    for (int j = 0; j < 8; ++j) {
        int node = gbase + q8 + j;
        float ps = 0.f, pd = 0.f;
        #pragma unroll
        for (int c = 0; c < 8; ++c) { ps += accs[c * 8 + j] * atts[c]; pd += accs[c * 8 + j] * attd[c]; }
        ps += __shfl_xor(ps, 1, 64); pd += __shfl_xor(pd, 1, 64);
        ps += __shfl_xor(ps, 2, 64); pd += __shfl_xor(pd, 2, 64);
        ps += __shfl_xor(ps, 4, 64); pd += __shfl_xor(pd, 4, 64);
        if (node < N_NODES) {
            uint4 pk;
            pk.x = bf2pack(accs[0 * 8 + j], accs[1 * 8 + j]);
            pk.y = bf2pack(accs[2 * 8 + j], accs[3 * 8 + j]);
            pk.z = bf2pack(accs[4 * 8 + j], accs[5 * 8 + j]);
            pk.w = bf2pack(accs[6 * 8 + j], accs[7 * 8 + j]);
            *(uint4*)(h1b + (size_t)node * 128 + m * 4) = pk;
            if ((m & 7) == 0) { as1[node * 4 + h] = ps; ad1[node * 4 + h] = pd; }
        }
    }
}

// ---------- scan3: finalize offs (computes own bsum prefix; scan2 eliminated) ----------
__global__ void k_scan3(int* __restrict__ offs, const int* __restrict__ bsum) {
    __shared__ int sd[256];
    int tid = threadIdx.x;
    int v = (tid < (int)blockIdx.x && tid < NB_SCAN) ? bsum[tid] : 0;
    sd[tid] = v;
    __syncthreads();
    for (int off = 128; off > 0; off >>= 1) {
        if (tid < off) sd[tid] += sd[tid + off];
        __syncthreads();
    }
    int prefix = sd[0];
    int i = blockIdx.x * 256 + tid;
    if (i < N_NODES) offs[i] += prefix;
    if (blockIdx.x == 0 && tid == 0) offs[N_NODES] = E_RAWN;
}

__global__ void k_scatter(const int* __restrict__ src, const int* __restrict__ dst,
                          const int* __restrict__ offs, int* __restrict__ cur,
                          int* __restrict__ esrc) {
    int e = blockIdx.x * blockDim.x + threadIdx.x;
    if (e < E_RAWN) {
        int d = dst[e];
        int pos = offs[d] + atomicAdd(&cur[d], 1);
        esrc[pos] = src[e];
    }
}

// ---------- Phase D: GAT layer 1 aggregation — single pass, unroll 4, bf16 in/out ----------
__global__ __launch_bounds__(256) void k_gat1(const unsigned* __restrict__ h1b,
                                              const float* __restrict__ as1,
                                              const float* __restrict__ ad1,
                                              const int* __restrict__ offs,
                                              const int* __restrict__ esrc,
                                              const float* __restrict__ b1,
                                              unsigned* __restrict__ hactb) {
    int wave = threadIdx.x >> 6, lane = threadIdx.x & 63;
    int i = blockIdx.x * 4 + wave;
    if (i >= N_NODES) return;
    int beg = offs[i], end = offs[i + 1];
    int h = lane >> 4;
    float adv = ad1[i * 4 + h];
    float w0 = __expf(leaky02(as1[i * 4 + h] + adv));   // self loop
    uint2 hv = *(const uint2*)(h1b + (size_t)i * 128 + lane * 2);
    float4 acc = make_float4(w0 * bflo(hv.x), w0 * bfhi(hv.x), w0 * bflo(hv.y), w0 * bfhi(hv.y));
    float d = w0;
    int p = beg;
    for (; p + 3 < end; p += 4) {
        int s0 = esrc[p], s1 = esrc[p + 1], s2 = esrc[p + 2], s3 = esrc[p + 3];
        uint2 hA = *(const uint2*)(h1b + (size_t)s0 * 128 + lane * 2);
        uint2 hB = *(const uint2*)(h1b + (size_t)s1 * 128 + lane * 2);
        uint2 hC = *(const uint2*)(h1b + (size_t)s2 * 128 + lane * 2);
        uint2 hD = *(const uint2*)(h1b + (size_t)s3 * 128 + lane * 2);
        float a0 = as1[s0 * 4 + h], a1 = as1[s1 * 4 + h];
        float a2 = as1[s2 * 4 + h], a3 = as1[s3 * 4 + h];
        float wA = __expf(leaky02(a0 + adv));
        float wB = __expf(leaky02(a1 + adv));
        float wC = __expf(leaky02(a2 + adv));
        float wD = __expf(leaky02(a3 + adv));
        d += (wA + wB) + (wC + wD);
        acc.x += wA * bflo(hA.x) + wB * bflo(hB.x) + wC * bflo(hC.x) + wD * bflo(hD.x);
        acc.y += wA * bfhi(hA.x) + wB * bfhi(hB.x) + wC * bfhi(hC.x) + wD * bfhi(hD.x);
        acc.z += wA * bflo(hA.y) + wB * bflo(hB.y) + wC * bflo(hC.y) + wD * bflo(hD.y);
        acc.w += wA * bfhi(hA.y) + wB * bfhi(hB.y) + wC * bfhi(hC.y) + wD * bfhi(hD.y);
    }
    for (; p < end; ++p) {
        int s0 = esrc[p];
        uint2 hA = *(const uint2*)(h1b + (size_t)s0 * 128 + lane * 2);
        float wA = __expf(leaky02(as1[s0 * 4 + h] + adv));
        d += wA;
        acc.x += wA * bflo(hA.x);
        acc.y += wA * bfhi(hA.x);
        acc.z += wA * bflo(hA.y);
        acc.w += wA * bfhi(hA.y);
    }
    float inv = 1.f / (d + 1e-16f);
    float4 bb = *(const float4*)(b1 + lane * 4);
    float rx = elu1(acc.x * inv + bb.x);
    float ry = elu1(acc.y * inv + bb.y);
    float rz = elu1(acc.z * inv + bb.z);
    float rw = elu1(acc.w * inv + bb.w);
    uint2 pk;
    pk.x = bf2pack(rx, ry);
    pk.y = bf2pack(rz, rw);
    *(uint2*)(hactb + (size_t)i * 128 + lane * 2) = pk;
}

// ---------- Phase E: h2 = hact(bf16) @ W2 (register-tiled, K-chunked LDS) — bf16 h2 out ----------
__global__ __launch_bounds__(256) void k_gemm2(const unsigned* __restrict__ hactb,
                                               const float* __restrict__ W2,
                                               const float* __restrict__ att_s2,
                                               const float* __restrict__ att_d2,
                                               unsigned short* __restrict__ h2b,
                                               float* __restrict__ as2, float* __restrict__ ad2) {
    __shared__ float hs[G2_NODES][68];   // one 64-k chunk, [node][k] f32, 272B rows
    int t = threadIdx.x;
    int gbase = blockIdx.x * G2_NODES;
    int m = t & 7, q = t >> 3;
    int c0 = m * 8, n0 = q * 4;
    float accs[32];                       // [col c][node j] = accs[c*4+j]
    #pragma unroll
    for (int i = 0; i < 32; ++i) accs[i] = 0.f;

    int sn = t >> 3;      // staging node (stride 32)
    int sko = t & 7;      // staging k-octet (8 bf16 per uint4)

    for (int kc = 0; kc < 4; ++kc) {
        __syncthreads();
        #pragma unroll
        for (int r = 0; r < 4; ++r) {
            int n = sn + r * 32;
            int g = gbase + n;
            uint4 v = (g < N_NODES)
                ? *(const uint4*)(hactb + (size_t)g * 128 + kc * 32 + sko * 4)
                : make_uint4(0u, 0u, 0u, 0u);
            float4 lo = make_float4(bflo(v.x), bfhi(v.x), bflo(v.y), bfhi(v.y));
            float4 hi = make_float4(bflo(v.z), bfhi(v.z), bflo(v.w), bfhi(v.w));
            *(float4*)(&hs[n][sko * 8])     = lo;
            *(float4*)(&hs[n][sko * 8 + 4]) = hi;
        }
        __syncthreads();
        const float* Wc = W2 + (size_t)kc * 64 * 64;
        for (int kk = 0; kk < 16; ++kk) {
            float4 xv0 = *(const float4*)(&hs[n0 + 0][kk * 4]);
            float4 xv1 = *(const float4*)(&hs[n0 + 1][kk * 4]);
            float4 xv2 = *(const float4*)(&hs[n0 + 2][kk * 4]);
            float4 xv3 = *(const float4*)(&hs[n0 + 3][kk * 4]);
            const float* x0 = (const float*)&xv0;
            const float* x1 = (const float*)&xv1;
            const float* x2 = (const float*)&xv2;
            const float* x3 = (const float*)&xv3;
            #pragma unroll
            for (int jj = 0; jj < 4; ++jj) {
                int k = kk * 4 + jj;
                float4 wa = *(const float4*)(Wc + (size_t)k * 64 + c0);
                float4 wb = *(const float4*)(Wc + (size_t)k * 64 + c0 + 4);
                float wv[8] = {wa.x, wa.y, wa.z, wa.w, wb.x, wb.y, wb.z, wb.w};
                float xj[4] = {x0[jj], x1[jj], x2[jj], x3[jj]};
                #pragma unroll
                for (int c = 0; c < 8; ++c)
                    #pragma unroll
                    for (int j = 0; j < 4; ++j)
                        accs[c * 4 + j] += wv[c] * xj[j];
            }
        }
    }

    float atts[8], attd[8];
    #pragma unroll
    for (int c = 0; c < 8; ++c) { atts[c] = att_s2[c0 + c]; attd[c] = att_d2[c0 + c]; }
    #pragma unroll
    for (int j = 0; j < 4; ++j) {
        int node = gbase + n0 + j;
        float ps = 0.f, pd = 0.f;
        #pragma unroll
        for (int c = 0; c < 8; ++c) { ps += accs[c * 4 + j] * atts[c]; pd += accs[c * 4 + j] * attd[c]; }
        ps += __shfl_xor(ps, 1, 64); pd += __shfl_xor(pd, 1, 64);
        ps += __shfl_xor(ps, 2, 64); pd += __shfl_xor(pd, 2, 64);
        ps += __shfl_xor(ps, 4, 64); pd += __shfl_xor(pd, 4, 64);
        if (node < N_NODES) {
            uint4 pk;
            pk.x = bf2pack(accs[0 * 4 + j], accs[1 * 4 + j]);
            pk.y = bf2pack(accs[2 * 4 + j], accs[3 * 4 + j]);
            pk.z = bf2pack(accs[4 * 4 + j], accs[5 * 4 + j]);
            pk.w = bf2pack(accs[6 * 4 + j], accs[7 * 4 + j]);
            *(uint4*)(h2b + (size_t)node * 64 + c0) = pk;
            if (m == 0) { as2[node] = ps; ad2[node] = pd; }
        }
    }
}

// ---------- Phase F: GAT layer 2 aggregation — single pass, unroll 4, bf16 gather, atomic pool ----------
__global__ __launch_bounds__(256) void k_gat2(const unsigned short* __restrict__ h2b,
                                              const float* __restrict__ as2,
                                              const float* __restrict__ ad2,
                                              const int* __restrict__ offs,
                                              const int* __restrict__ esrc,
                                              const int* __restrict__ batch,
                                              float* __restrict__ gpool) {
    int wave = threadIdx.x >> 6, lane = threadIdx.x & 63;
    int i = blockIdx.x * 4 + wave;
    if (i >= N_NODES) return;
    int beg = offs[i], end = offs[i + 1];
    float adv = ad2[i];
    float w0 = __expf(leaky02(as2[i] + adv));   // self loop
    float d = w0;
    float acc = w0 * bfs(h2b[(size_t)i * 64 + lane]);
    int p = beg;
    for (; p + 3 < end; p += 4) {
        int s0 = esrc[p], s1 = esrc[p + 1], s2 = esrc[p + 2], s3 = esrc[p + 3];
        float hA = bfs(h2b[(size_t)s0 * 64 + lane]);
        float hB = bfs(h2b[(size_t)s1 * 64 + lane]);
        float hC = bfs(h2b[(size_t)s2 * 64 + lane]);
        float hD = bfs(h2b[(size_t)s3 * 64 + lane]);
        float wA = __expf(leaky02(as2[s0] + adv));
        float wB = __expf(leaky02(as2[s1] + adv));
        float wC = __expf(leaky02(as2[s2] + adv));
        float wD = __expf(leaky02(as2[s3] + adv));
        d += (wA + wB) + (wC + wD);
        acc += wA * hA + wB * hB + wC * hC + wD * hD;
    }
    for (; p < end; ++p) {
        int s0 = esrc[p];
        float wA = __expf(leaky02(as2[s0] + adv));
        d += wA;
        acc += wA * bfs(h2b[(size_t)s0 * 64 + lane]);
    }
    int b = batch[i];
    atomicAdd(&gpool[(size_t)b * 64 + lane], acc / (d + 1e-16f));
}

// ---------- Phase H: per-graph bias + prediction head ----------
__device__ __forceinline__ int lower_bound_i(const int* a, int n, int v) {
    int lo = 0, hi = n;
    while (lo < hi) { int mid = (lo + hi) >> 1; if (a[mid] < v) lo = mid + 1; else hi = mid; }
    return lo;
}

__global__ void k_head(const float* __restrict__ gpool, const int* __restrict__ batch,
                       const float* __restrict__ b2,
                       const float* __restrict__ Wp1, const float* __restrict__ bp1,
                       const float* __restrict__ Wp2, const float* __restrict__ bp2,
                       float* __restrict__ out) {
    __shared__ float tot[64];
    __shared__ float hred[32];
    int b = blockIdx.x;
    int t = threadIdx.x;
    int lo = lower_bound_i(batch, N_NODES, b);
    int hi = lower_bound_i(batch, N_NODES, b + 1);
    tot[t] = gpool[(size_t)b * 64 + t] + (float)(hi - lo) * b2[t];
    __syncthreads();
    if (t < 32) {
        float hj = bp1[t];
        #pragma unroll
        for (int k = 0; k < 64; ++k) hj += tot[k] * Wp1[k * 32 + t];
        hred[t] = elu1(hj) * Wp2[t];
    }
    __syncthreads();
    if (t == 0) {
        float a = bp2[0];
        #pragma unroll
        for (int j = 0; j < 32; ++j) a += hred[j];
        out[b] = a;
    }
}

extern "C" void kernel_launch(void* const* d_in, const int* in_sizes, int n_in,
                              void* d_out, int out_size, void* d_ws, size_t ws_size,
                              hipStream_t stream) {
    const float* x      = (const float*)d_in[0];
    const int*   edge   = (const int*)d_in[1];
    const int*   batch  = (const int*)d_in[2];
    const float* w_sa1  = (const float*)d_in[3];
    const float* b_sa1  = (const float*)d_in[4];
    const float* w_sa2  = (const float*)d_in[5];
    const float* b_sa2  = (const float*)d_in[6];
    const float* W1     = (const float*)d_in[7];
    const float* att_s1 = (const float*)d_in[8];
    const float* att_d1 = (const float*)d_in[9];
    const float* b1     = (const float*)d_in[10];
    const float* W2     = (const float*)d_in[11];
    const float* att_s2 = (const float*)d_in[12];
    const float* att_d2 = (const float*)d_in[13];
    const float* b2     = (const float*)d_in[14];
    const float* Wp1    = (const float*)d_in[15];
    const float* bp1    = (const float*)d_in[16];
    const float* Wp2    = (const float*)d_in[17];
    const float* bp2    = (const float*)d_in[18];
    float* out = (float*)d_out;

    const int* e_src = edge;
    const int* e_dst = edge + E_RAWN;

    char* base = (char*)d_ws;
    size_t off = 0;
    auto alloc = [&](size_t bytes) -> void* {
        void* p = base + off;
        off = (off + bytes + 255) & ~(size_t)255;
        return p;
    };
    // --- zeroed region (one memset covers all of these, including align padding) ---
    float* ssum   = (float*)alloc((NSUB * FEAT + NSUB) * 4);
    float* scnt   = ssum + NSUB * FEAT;
    int*   counts = (int*)alloc((size_t)N_NODES * 2 * 4);
    int*   cursor = counts + N_NODES;
    float* gpool  = (float*)alloc((size_t)NGRAPH * HID * 4);
    size_t zero_bytes = off;
    // --- rest ---
    float* wsub   = (float*)alloc(NSUB * 4);
    float* as1    = (float*)alloc((size_t)N_NODES * 4 * 4);
    float* ad1    = (float*)alloc((size_t)N_NODES * 4 * 4);
    float* as2    = (float*)alloc((size_t)N_NODES * 4);
    float* ad2    = (float*)alloc((size_t)N_NODES * 4);
    int*   offs   = (int*)alloc((size_t)(N_NODES + 1) * 4);
    int*   bsum   = (int*)alloc(256 * 4);
    int*   esrc   = (int*)alloc((size_t)E_RAWN * 4);
    unsigned* h1b   = (unsigned*)alloc((size_t)N_NODES * 128 * 4);       // bf16-packed h1
    unsigned* hactb = (unsigned*)alloc((size_t)N_NODES * 128 * 4);       // bf16-packed hact
    unsigned short* h2b = (unsigned short*)alloc((size_t)N_NODES * 64 * 2);  // bf16-packed h2

    (void)hipMemsetAsync(base, 0, zero_bytes, stream);

    k_prep<<<512, 256, 0, stream>>>(x, ssum, scnt, e_dst, counts);
    k_mlp_scan1<<<NB_SCAN + 1, 256, 0, stream>>>(counts, offs, bsum,
                                                 ssum, scnt, w_sa1, b_sa1, w_sa2, b_sa2, wsub);
    k_gemm1<<<(N_NODES + 63) / 64, 256, 0, stream>>>(x, wsub, W1, att_s1, att_d1, h1b, as1, ad1);

    k_scan3<<<NB_SCAN, 256, 0, stream>>>(offs, bsum);
    k_scatter<<<(E_RAWN + 255) / 256, 256, 0, stream>>>(e_src, e_dst, offs, cursor, esrc);

    k_gat1<<<(N_NODES + 3) / 4, 256, 0, stream>>>(h1b, as1, ad1, offs, esrc, b1, hactb);
    k_gemm2<<<(N_NODES + G2_NODES - 1) / G2_NODES, 256, 0, stream>>>(hactb, W2, att_s2, att_d2, h2b, as2, ad2);
    k_gat2<<<(N_NODES + 3) / 4, 256, 0, stream>>>(h2b, as2, ad2, offs, esrc, batch, gpool);
    k_head<<<NGRAPH, 64, 0, stream>>>(gpool, batch, b2, Wp1, bp1, Wp2, bp2, out);
}

// Round 14
// 295.424 us; speedup vs baseline: 1.0104x; 1.0104x over previous
//
#include <hip/hip_runtime.h>
#include <math.h>

#define N_NODES 50000
#define E_RAWN  600000
#define FEAT    64
#define HID     64
#define HEADS   4
#define NSUB    32
#define NGRAPH  128
#define NB_SCAN ((N_NODES + 255) / 256)   // 196
#define G2_NODES 128
#define NBLK_G1 ((N_NODES + 63) / 64)     // 782

__device__ __forceinline__ float leaky02(float v) { return v >= 0.f ? v : 0.2f * v; }
__device__ __forceinline__ float elu1(float v)    { return v > 0.f ? v : expm1f(v); }

// bf16 pack/unpack (RNE), 2 per uint
__device__ __forceinline__ unsigned bf2pack(float a, float b) {
    unsigned ua = __float_as_uint(a), ub = __float_as_uint(b);
    ua = (ua + 0x7FFFu + ((ua >> 16) & 1u)) >> 16;
    ub = (ub + 0x7FFFu + ((ub >> 16) & 1u)) >> 16;
    return ua | (ub << 16);
}
__device__ __forceinline__ float bflo(unsigned p) { return __uint_as_float(p << 16); }
__device__ __forceinline__ float bfhi(unsigned p) { return __uint_as_float(p & 0xFFFF0000u); }
__device__ __forceinline__ float bfs(unsigned short v) { return __uint_as_float((unsigned)v << 16); }

// ---------- Phase A merged: substructure accumulate (blocks 0-255) + edge count (blocks 256-511) ----------
__global__ void k_prep(const float* __restrict__ x,
                       float* __restrict__ ssum, float* __restrict__ scnt,
                       const int* __restrict__ dst, int* __restrict__ cnt) {
    int tid = threadIdx.x;
    if (blockIdx.x < 256) {
        __shared__ float lsum[NSUB * FEAT];
        __shared__ float lcnt[NSUB];
        for (int i = tid; i < NSUB * FEAT; i += 256) lsum[i] = 0.f;
        if (tid < NSUB) lcnt[tid] = 0.f;
        __syncthreads();
        const int total = N_NODES * FEAT;
        for (int idx = blockIdx.x * 256 + tid; idx < total; idx += 256 * 256) {
            int node = idx >> 6, f = idx & 63;
            int sid = (int)x[node * FEAT + 5];
            atomicAdd(&lsum[sid * FEAT + f], x[idx]);
            if (f == 0) atomicAdd(&lcnt[sid], 1.f);
        }
        __syncthreads();
        for (int i = tid; i < NSUB * FEAT; i += 256) atomicAdd(&ssum[i], lsum[i]);
        if (tid < NSUB) atomicAdd(&scnt[tid], lcnt[tid]);
    } else {
        for (int e = (blockIdx.x - 256) * 256 + tid; e < E_RAWN; e += 256 * 256)
            atomicAdd(&cnt[dst[e]], 1);
    }
}

// ---------- Merged: scan1 (blocks 0-195) + substructure MLP/softmax (block 196) ----------
__global__ void k_mlp_scan1(const int* __restrict__ cnt, int* __restrict__ offs, int* __restrict__ bsum,
                            const float* __restrict__ ssum, const float* __restrict__ scnt,
                            const float* __restrict__ w_sa1, const float* __restrict__ b_sa1,
                            const float* __restrict__ w_sa2, const float* __restrict__ b_sa2,
                            float* __restrict__ wsub) {
    int tid = threadIdx.x;
    if (blockIdx.x == NB_SCAN) {
        __shared__ float logits[NSUB];
        int s = tid;
        if (s < NSUB) {
            float c = fmaxf(scnt[s], 1.f);
            float sm[FEAT];
            for (int k = 0; k < FEAT; k++) sm[k] = ssum[s * FEAT + k] / c;
            float logit = b_sa2[0];
            for (int j = 0; j < 32; j++) {
                float hj = b_sa1[j];
                for (int k = 0; k < FEAT; k++) hj += sm[k] * w_sa1[k * 32 + j];
                hj = leaky02(hj);
                logit += hj * w_sa2[j];
            }
            logits[s] = logit;
        }
        __syncthreads();
        if (s < NSUB) {
            float m = -1e30f;
            for (int i = 0; i < NSUB; i++) m = fmaxf(m, logits[i]);
            float dsum = 0.f;
            for (int i = 0; i < NSUB; i++) dsum += expf(logits[i] - m);
            wsub[s] = expf(logits[s] - m) / dsum;
        }
        return;
    }
    __shared__ int sd[256];
    int i = blockIdx.x * 256 + tid;
    int v = (i < N_NODES) ? cnt[i] : 0;
    sd[tid] = v;
    for (int off = 1; off < 256; off <<= 1) {
        __syncthreads();
        int tv = (tid >= off) ? sd[tid - off] : 0;
        __syncthreads();
        sd[tid] += tv;
    }
    __syncthreads();
    if (i < N_NODES) offs[i] = sd[tid] - v;
    if (tid == 255) bsum[blockIdx.x] = sd[255];
}

// ---------- Phase B merged: gemm1 (blocks 0-781) + scan3 finalize (blocks 782-977) ----------
__global__ __launch_bounds__(256) void k_gemm1_scan3(const float* __restrict__ x,
                                                     const float* __restrict__ wsub,
                                                     const float* __restrict__ W1,
                                                     const float* __restrict__ att_s1,
                                                     const float* __restrict__ att_d1,
                                                     unsigned* __restrict__ h1b,
                                                     float* __restrict__ as1, float* __restrict__ ad1,
                                                     int* __restrict__ offs, const int* __restrict__ bsum) {
    int t = threadIdx.x;
    if (blockIdx.x >= NBLK_G1) {
        // ---- scan3 role: add bsum prefix (self-computed) to offs ----
        __shared__ int sd[256];
        int b = blockIdx.x - NBLK_G1;
        int v = (t < b && t < NB_SCAN) ? bsum[t] : 0;
        sd[t] = v;
        __syncthreads();
        for (int off = 128; off > 0; off >>= 1) {
            if (t < off) sd[t] += sd[t + off];
            __syncthreads();
        }
        int prefix = sd[0];
        int i = b * 256 + t;
        if (i < N_NODES) offs[i] += prefix;
        if (b == 0 && t == 0) offs[N_NODES] = E_RAWN;
        return;
    }
    __shared__ float xs[65][68];    // [k][node], 272B rows
    __shared__ float ws[16][260];   // one 16-row W1 chunk, [k][col]
    int gbase = blockIdx.x * 64;
    for (int idx = t; idx < 64 * 64; idx += 256) {
        int n = idx >> 6, f = idx & 63;
        int g = gbase + n;
        xs[f][n] = (g < N_NODES) ? x[(size_t)g * FEAT + f] : 0.f;
    }
    __syncthreads();
    if (t < 64) {
        int sid = (int)xs[5][t];
        xs[64][t] = wsub[sid & (NSUB - 1)];
    }

    int m = t & 31, q = t >> 5;
    int c0 = m * 8, q8 = q * 8;
    float accs[64];                 // [col c][node j] = accs[c*8+j]
    #pragma unroll
    for (int i = 0; i < 64; ++i) accs[i] = 0.f;

    for (int kc = 0; kc < 4; ++kc) {
        __syncthreads();            // ws reuse guard (covers xs[64] write before kc=0)
        #pragma unroll
        for (int s = 0; s < 16; ++s)
            ws[s][t] = W1[(size_t)(kc * 16 + s) * 256 + t];
        __syncthreads();
        #pragma unroll
        for (int kk = 0; kk < 16; ++kk) {
            float4 wa = *(const float4*)(&ws[kk][c0]);
            float4 wb = *(const float4*)(&ws[kk][c0 + 4]);
            float4 xa = *(const float4*)(&xs[kc * 16 + kk][q8]);
            float4 xb = *(const float4*)(&xs[kc * 16 + kk][q8 + 4]);
            float wv[8] = {wa.x, wa.y, wa.z, wa.w, wb.x, wb.y, wb.z, wb.w};
            float xv[8] = {xa.x, xa.y, xa.z, xa.w, xb.x, xb.y, xb.z, xb.w};
            #pragma unroll
            for (int c = 0; c < 8; ++c)
                #pragma unroll
                for (int j = 0; j < 8; ++j)
                    accs[c * 8 + j] += wv[c] * xv[j];
        }
    }
    {   // k = 64: atom_w row, direct from global (1 KB, L2-hot)
        float4 wa = *(const float4*)(W1 + (size_t)64 * 256 + c0);
        float4 wb = *(const float4*)(W1 + (size_t)64 * 256 + c0 + 4);
        float4 xa = *(const float4*)(&xs[64][q8]);
        float4 xb = *(const float4*)(&xs[64][q8 + 4]);
        float wv[8] = {wa.x, wa.y, wa.z, wa.w, wb.x, wb.y, wb.z, wb.w};
        float xv[8] = {xa.x, xa.y, xa.z, xa.w, xb.x, xb.y, xb.z, xb.w};
        #pragma unroll
        for (int c = 0; c < 8; ++c)
            #pragma unroll
            for (int j = 0; j < 8; ++j)
                accs[c * 8 + j] += wv[c] * xv[j];
    }

    float atts[8], attd[8];
    #pragma unroll
    for (int c = 0; c < 8; ++c) { atts[c] = att_s1[c0 + c]; attd[c] = att_d1[c0 + c]; }
    int h = m >> 3;
    #pragma unroll
    for (int j = 0; j < 8; ++j) {
        int node = gbase + q8 + j;
        float ps = 0.f, pd = 0.f;
        #pragma unroll
        for (int c = 0; c < 8; ++c) { ps += accs[c * 8 + j] * atts[c]; pd += accs[c * 8 + j] * attd[c]; }
        ps += __shfl_xor(ps, 1, 64); pd += __shfl_xor(pd, 1, 64);
        ps += __shfl_xor(ps, 2, 64); pd += __shfl_xor(pd, 2, 64);
        ps += __shfl_xor(ps, 4, 64); pd += __shfl_xor(pd, 4, 64);
        if (node < N_NODES) {
            uint4 pk;
            pk.x = bf2pack(accs[0 * 8 + j], accs[1 * 8 + j]);
            pk.y = bf2pack(accs[2 * 8 + j], accs[3 * 8 + j]);
            pk.z = bf2pack(accs[4 * 8 + j], accs[5 * 8 + j]);
            pk.w = bf2pack(accs[6 * 8 + j], accs[7 * 8 + j]);
            *(uint4*)(h1b + (size_t)node * 128 + m * 4) = pk;
            if ((m & 7) == 0) { as1[node * 4 + h] = ps; ad1[node * 4 + h] = pd; }
        }
    }
}

__global__ void k_scatter(const int* __restrict__ src, const int* __restrict__ dst,
                          const int* __restrict__ offs, int* __restrict__ cur,
                          int* __restrict__ esrc) {
    int e = blockIdx.x * blockDim.x + threadIdx.x;
    if (e < E_RAWN) {
        int d = dst[e];
        int pos = offs[d] + atomicAdd(&cur[d], 1);
        esrc[pos] = src[e];
    }
}

// ---------- Phase D: GAT layer 1 aggregation — single pass, unroll 4, bf16 in/out ----------
__global__ __launch_bounds__(256) void k_gat1(const unsigned* __restrict__ h1b,
                                              const float* __restrict__ as1,
                                              const float* __restrict__ ad1,
                                              const int* __restrict__ offs,
                                              const int* __restrict__ esrc,
                                              const float* __restrict__ b1,
                                              unsigned* __restrict__ hactb) {
    int wave = threadIdx.x >> 6, lane = threadIdx.x & 63;
    int i = blockIdx.x * 4 + wave;
    if (i >= N_NODES) return;
    int beg = offs[i], end = offs[i + 1];
    int h = lane >> 4;
    float adv = ad1[i * 4 + h];
    float w0 = __expf(leaky02(as1[i * 4 + h] + adv));   // self loop
    uint2 hv = *(const uint2*)(h1b + (size_t)i * 128 + lane * 2);
    float4 acc = make_float4(w0 * bflo(hv.x), w0 * bfhi(hv.x), w0 * bflo(hv.y), w0 * bfhi(hv.y));
    float d = w0;
    int p = beg;
    for (; p + 3 < end; p += 4) {
        int s0 = esrc[p], s1 = esrc[p + 1], s2 = esrc[p + 2], s3 = esrc[p + 3];
        uint2 hA = *(const uint2*)(h1b + (size_t)s0 * 128 + lane * 2);
        uint2 hB = *(const uint2*)(h1b + (size_t)s1 * 128 + lane * 2);
        uint2 hC = *(const uint2*)(h1b + (size_t)s2 * 128 + lane * 2);
        uint2 hD = *(const uint2*)(h1b + (size_t)s3 * 128 + lane * 2);
        float a0 = as1[s0 * 4 + h], a1 = as1[s1 * 4 + h];
        float a2 = as1[s2 * 4 + h], a3 = as1[s3 * 4 + h];
        float wA = __expf(leaky02(a0 + adv));
        float wB = __expf(leaky02(a1 + adv));
        float wC = __expf(leaky02(a2 + adv));
        float wD = __expf(leaky02(a3 + adv));
        d += (wA + wB) + (wC + wD);
        acc.x += wA * bflo(hA.x) + wB * bflo(hB.x) + wC * bflo(hC.x) + wD * bflo(hD.x);
        acc.y += wA * bfhi(hA.x) + wB * bfhi(hB.x) + wC * bfhi(hC.x) + wD * bfhi(hD.x);
        acc.z += wA * bflo(hA.y) + wB * bflo(hB.y) + wC * bflo(hC.y) + wD * bflo(hD.y);
        acc.w += wA * bfhi(hA.y) + wB * bfhi(hB.y) + wC * bfhi(hC.y) + wD * bfhi(hD.y);
    }
    for (; p < end; ++p) {
        int s0 = esrc[p];
        uint2 hA = *(const uint2*)(h1b + (size_t)s0 * 128 + lane * 2);
        float wA = __expf(leaky02(as1[s0 * 4 + h] + adv));
        d += wA;
        acc.x += wA * bflo(hA.x);
        acc.y += wA * bfhi(hA.x);
        acc.z += wA * bflo(hA.y);
        acc.w += wA * bfhi(hA.y);
    }
    float inv = 1.f / (d + 1e-16f);
    float4 bb = *(const float4*)(b1 + lane * 4);
    float rx = elu1(acc.x * inv + bb.x);
    float ry = elu1(acc.y * inv + bb.y);
    float rz = elu1(acc.z * inv + bb.z);
    float rw = elu1(acc.w * inv + bb.w);
    uint2 pk;
    pk.x = bf2pack(rx, ry);
    pk.y = bf2pack(rz, rw);
    *(uint2*)(hactb + (size_t)i * 128 + lane * 2) = pk;
}

// ---------- Phase E: h2 = hact(bf16) @ W2 (register-tiled, K-chunked LDS) — bf16 h2 out ----------
__global__ __launch_bounds__(256) void k_gemm2(const unsigned* __restrict__ hactb,
                                               const float* __restrict__ W2,
                                               const float* __restrict__ att_s2,
                                               const float* __restrict__ att_d2,
                                               unsigned short* __restrict__ h2b,
                                               float* __restrict__ as2, float* __restrict__ ad2) {
    __shared__ float hs[G2_NODES][68];   // one 64-k chunk, [node][k] f32, 272B rows
    int t = threadIdx.x;
    int gbase = blockIdx.x * G2_NODES;
    int m = t & 7, q = t >> 3;
    int c0 = m * 8, n0 = q * 4;
    float accs[32];                       // [col c][node j] = accs[c*4+j]
    #pragma unroll
    for (int i = 0; i < 32; ++i) accs[i] = 0.f;

    int sn = t >> 3;      // staging node (stride 32)
    int sko = t & 7;      // staging k-octet (8 bf16 per uint4)

    for (int kc = 0; kc < 4; ++kc) {
        __syncthreads();
        #pragma unroll
        for (int r = 0; r < 4; ++r) {
            int n = sn + r * 32;
            int g = gbase + n;
            uint4 v = (g < N_NODES)
                ? *(const uint4*)(hactb + (size_t)g * 128 + kc * 32 + sko * 4)
                : make_uint4(0u, 0u, 0u, 0u);
            float4 lo = make_float4(bflo(v.x), bfhi(v.x), bflo(v.y), bfhi(v.y));
            float4 hi = make_float4(bflo(v.z), bfhi(v.z), bflo(v.w), bfhi(v.w));
            *(float4*)(&hs[n][sko * 8])     = lo;
            *(float4*)(&hs[n][sko * 8 + 4]) = hi;
        }
        __syncthreads();
        const float* Wc = W2 + (size_t)kc * 64 * 64;
        for (int kk = 0; kk < 16; ++kk) {
            float4 xv0 = *(const float4*)(&hs[n0 + 0][kk * 4]);
            float4 xv1 = *(const float4*)(&hs[n0 + 1][kk * 4]);
            float4 xv2 = *(const float4*)(&hs[n0 + 2][kk * 4]);
            float4 xv3 = *(const float4*)(&hs[n0 + 3][kk * 4]);
            const float* x0 = (const float*)&xv0;
            const float* x1 = (const float*)&xv1;
            const float* x2 = (const float*)&xv2;
            const float* x3 = (const float*)&xv3;
            #pragma unroll
            for (int jj = 0; jj < 4; ++jj) {
                int k = kk * 4 + jj;
                float4 wa = *(const float4*)(Wc + (size_t)k * 64 + c0);
                float4 wb = *(const float4*)(Wc + (size_t)k * 64 + c0 + 4);
                float wv[8] = {wa.x, wa.y, wa.z, wa.w, wb.x, wb.y, wb.z, wb.w};
                float xj[4] = {x0[jj], x1[jj], x2[jj], x3[jj]};
                #pragma unroll
                for (int c = 0; c < 8; ++c)
                    #pragma unroll
                    for (int j = 0; j < 4; ++j)
                        accs[c * 4 + j] += wv[c] * xj[j];
            }
        }
    }

    float atts[8], attd[8];
    #pragma unroll
    for (int c = 0; c < 8; ++c) { atts[c] = att_s2[c0 + c]; attd[c] = att_d2[c0 + c]; }
    #pragma unroll
    for (int j = 0; j < 4; ++j) {
        int node = gbase + n0 + j;
        float ps = 0.f, pd = 0.f;
        #pragma unroll
        for (int c = 0; c < 8; ++c) { ps += accs[c * 4 + j] * atts[c]; pd += accs[c * 4 + j] * attd[c]; }
        ps += __shfl_xor(ps, 1, 64); pd += __shfl_xor(pd, 1, 64);
        ps += __shfl_xor(ps, 2, 64); pd += __shfl_xor(pd, 2, 64);
        ps += __shfl_xor(ps, 4, 64); pd += __shfl_xor(pd, 4, 64);
        if (node < N_NODES) {
            uint4 pk;
            pk.x = bf2pack(accs[0 * 4 + j], accs[1 * 4 + j]);
            pk.y = bf2pack(accs[2 * 4 + j], accs[3 * 4 + j]);
            pk.z = bf2pack(accs[4 * 4 + j], accs[5 * 4 + j]);
            pk.w = bf2pack(accs[6 * 4 + j], accs[7 * 4 + j]);
            *(uint4*)(h2b + (size_t)node * 64 + c0) = pk;
            if (m == 0) { as2[node] = ps; ad2[node] = pd; }
        }
    }
}

// ---------- Phase F: GAT layer 2 aggregation — single pass, unroll 8 (L2-latency-bound regime) ----------
__global__ __launch_bounds__(256) void k_gat2(const unsigned short* __restrict__ h2b,
                                              const float* __restrict__ as2,
                                              const float* __restrict__ ad2,
                                              const int* __restrict__ offs,
                                              const int* __restrict__ esrc,
                                              float* __restrict__ rbuf) {
    int wave = threadIdx.x >> 6, lane = threadIdx.x & 63;
    int i = blockIdx.x * 4 + wave;
    if (i >= N_NODES) return;
    int beg = offs[i], end = offs[i + 1];
    float adv = ad2[i];
    float w0 = __expf(leaky02(as2[i] + adv));   // self loop
    float d = w0;
    float acc = w0 * bfs(h2b[(size_t)i * 64 + lane]);
    int p = beg;
    for (; p + 7 < end; p += 8) {
        int s0 = esrc[p],     s1 = esrc[p + 1], s2 = esrc[p + 2], s3 = esrc[p + 3];
        int s4 = esrc[p + 4], s5 = esrc[p + 5], s6 = esrc[p + 6], s7 = esrc[p + 7];
        float hA = bfs(h2b[(size_t)s0 * 64 + lane]);
        float hB = bfs(h2b[(size_t)s1 * 64 + lane]);
        float hC = bfs(h2b[(size_t)s2 * 64 + lane]);
        float hD = bfs(h2b[(size_t)s3 * 64 + lane]);
        float hE = bfs(h2b[(size_t)s4 * 64 + lane]);
        float hF = bfs(h2b[(size_t)s5 * 64 + lane]);
        float hG = bfs(h2b[(size_t)s6 * 64 + lane]);
        float hH = bfs(h2b[(size_t)s7 * 64 + lane]);
        float wA = __expf(leaky02(as2[s0] + adv));
        float wB = __expf(leaky02(as2[s1] + adv));
        float wC = __expf(leaky02(as2[s2] + adv));
        float wD = __expf(leaky02(as2[s3] + adv));
        float wE = __expf(leaky02(as2[s4] + adv));
        float wF = __expf(leaky02(as2[s5] + adv));
        float wG = __expf(leaky02(as2[s6] + adv));
        float wH = __expf(leaky02(as2[s7] + adv));
        d += ((wA + wB) + (wC + wD)) + ((wE + wF) + (wG + wH));
        acc += (wA * hA + wB * hB + wC * hC + wD * hD)
             + (wE * hE + wF * hF + wG * hG + wH * hH);
    }
    for (; p < end; ++p) {
        int s0 = esrc[p];
        float wA = __expf(leaky02(as2[s0] + adv));
        d += wA;
        acc += wA * bfs(h2b[(size_t)s0 * 64 + lane]);
    }
    rbuf[(size_t)i * 64 + lane] = acc / (d + 1e-16f);
}

// ---------- Phase G+H fused: pool per graph + prediction head ----------
__device__ __forceinline__ int lower_bound_i(const int* a, int n, int v) {
    int lo = 0, hi = n;
    while (lo < hi) { int mid = (lo + hi) >> 1; if (a[mid] < v) lo = mid + 1; else hi = mid; }
    return lo;
}

__global__ void k_pool_head(const float* __restrict__ rbuf, const int* __restrict__ batch,
                            const float* __restrict__ b2,
                            const float* __restrict__ Wp1, const float* __restrict__ bp1,
                            const float* __restrict__ Wp2, const float* __restrict__ bp2,
                            float* __restrict__ out) {
    __shared__ float red[4][64];
    __shared__ float tot[64];
    __shared__ float hred[32];
    int b = blockIdx.x;
    int lo = lower_bound_i(batch, N_NODES, b);
    int hi = lower_bound_i(batch, N_NODES, b + 1);
    int t = threadIdx.x;
    int c = t & 63, rg = t >> 6;
    float s = 0.f;
    for (int r = lo + rg; r < hi; r += 4) s += rbuf[(size_t)r * 64 + c];
    red[rg][c] = s;
    __syncthreads();
    if (rg == 0) tot[c] = red[0][c] + red[1][c] + red[2][c] + red[3][c] + (float)(hi - lo) * b2[c];
    __syncthreads();
    if (t < 32) {
        float hj = bp1[t];
        #pragma unroll
        for (int k = 0; k < 64; ++k) hj += tot[k] * Wp1[k * 32 + t];
        hred[t] = elu1(hj) * Wp2[t];
    }
    __syncthreads();
    if (t == 0) {
        float a = bp2[0];
        #pragma unroll
        for (int j = 0; j < 32; ++j) a += hred[j];
        out[b] = a;
    }
}

extern "C" void kernel_launch(void* const* d_in, const int* in_sizes, int n_in,
                              void* d_out, int out_size, void* d_ws, size_t ws_size,
                              hipStream_t stream) {
    const float* x      = (const float*)d_in[0];
    const int*   edge   = (const int*)d_in[1];
    const int*   batch  = (const int*)d_in[2];
    const float* w_sa1  = (const float*)d_in[3];
    const float* b_sa1  = (const float*)d_in[4];
    const float* w_sa2  = (const float*)d_in[5];
    const float* b_sa2  = (const float*)d_in[6];
    const float* W1     = (const float*)d_in[7];
    const float* att_s1 = (const float*)d_in[8];
    const float* att_d1 = (const float*)d_in[9];
    const float* b1     = (const float*)d_in[10];
    const float* W2     = (const float*)d_in[11];
    const float* att_s2 = (const float*)d_in[12];
    const float* att_d2 = (const float*)d_in[13];
    const float* b2     = (const float*)d_in[14];
    const float* Wp1    = (const float*)d_in[15];
    const float* bp1    = (const float*)d_in[16];
    const float* Wp2    = (const float*)d_in[17];
    const float* bp2    = (const float*)d_in[18];
    float* out = (float*)d_out;

    const int* e_src = edge;
    const int* e_dst = edge + E_RAWN;

    char* base = (char*)d_ws;
    size_t off = 0;
    auto alloc = [&](size_t bytes) -> void* {
        void* p = base + off;
        off = (off + bytes + 255) & ~(size_t)255;
        return p;
    };
    // --- zeroed region (one memset covers all of these, including align padding) ---
    float* ssum   = (float*)alloc((NSUB * FEAT + NSUB) * 4);
    float* scnt   = ssum + NSUB * FEAT;
    int*   counts = (int*)alloc((size_t)N_NODES * 2 * 4);
    int*   cursor = counts + N_NODES;
    size_t zero_bytes = off;
    // --- rest ---
    float* wsub   = (float*)alloc(NSUB * 4);
    float* as1    = (float*)alloc((size_t)N_NODES * 4 * 4);
    float* ad1    = (float*)alloc((size_t)N_NODES * 4 * 4);
    float* as2    = (float*)alloc((size_t)N_NODES * 4);
    float* ad2    = (float*)alloc((size_t)N_NODES * 4);
    int*   offs   = (int*)alloc((size_t)(N_NODES + 1) * 4);
    int*   bsum   = (int*)alloc(256 * 4);
    int*   esrc   = (int*)alloc((size_t)E_RAWN * 4);
    unsigned* h1b   = (unsigned*)alloc((size_t)N_NODES * 128 * 4);       // bf16-packed h1
    unsigned* hactb = (unsigned*)alloc((size_t)N_NODES * 128 * 4);       // bf16-packed hact
    unsigned short* h2b = (unsigned short*)alloc((size_t)N_NODES * 64 * 2);  // bf16-packed h2
    float* rbuf   = (float*)alloc((size_t)N_NODES * 64 * 4);

    (void)hipMemsetAsync(base, 0, zero_bytes, stream);

    k_prep<<<512, 256, 0, stream>>>(x, ssum, scnt, e_dst, counts);
    k_mlp_scan1<<<NB_SCAN + 1, 256, 0, stream>>>(counts, offs, bsum,
                                                 ssum, scnt, w_sa1, b_sa1, w_sa2, b_sa2, wsub);
    k_gemm1_scan3<<<NBLK_G1 + NB_SCAN, 256, 0, stream>>>(x, wsub, W1, att_s1, att_d1,
                                                         h1b, as1, ad1, offs, bsum);
    k_scatter<<<(E_RAWN + 255) / 256, 256, 0, stream>>>(e_src, e_dst, offs, cursor, esrc);

    k_gat1<<<(N_NODES + 3) / 4, 256, 0, stream>>>(h1b, as1, ad1, offs, esrc, b1, hactb);
    k_gemm2<<<(N_NODES + G2_NODES - 1) / G2_NODES, 256, 0, stream>>>(hactb, W2, att_s2, att_d2, h2b, as2, ad2);
    k_gat2<<<(N_NODES + 3) / 4, 256, 0, stream>>>(h2b, as2, ad2, offs, esrc, rbuf);
    k_pool_head<<<NGRAPH, 256, 0, stream>>>(rbuf, batch, b2, Wp1, bp1, Wp2, bp2, out);
}